// Round 6
// baseline (241.504 us; speedup 1.0000x reference)
//
#include <hip/hip_runtime.h>

#define NUM_CLASSES 19
#define N_BLOCKS 1024   // 32 batches x 32 slab-rows

// Single fused kernel. One block per 32-row x 1024-col slab of targets
// (128 KB contiguous). Block computes its partial BCE sum, publishes it,
// and the LAST block to finish (fence+counter) reduces all partials and
// writes the final mean. No second dispatch.
//
// d_ws layout: [0] int counter (memset to 0 on stream each call),
//              [64..] float partial[N_BLOCKS] (256-byte offset).
__global__ __launch_bounds__(256) void seg_loss_fused(
    const float* __restrict__ preds,
    const int*   __restrict__ targets,
    float*       __restrict__ out,
    int*         __restrict__ counter,
    float*       __restrict__ partial,
    float inv_total)
{
    const int tid = threadIdx.x;
    const int bid = blockIdx.x;
    // slab base element = blockIdx.x * 32*1024
    const int* base = targets + (bid << 15);

    // ---- stream the slab linearly: 32 iterations x one full 4 KB row ----
    unsigned mask = 0u;
    #pragma unroll 4
    for (int r = 0; r < 32; ++r) {
        const int4 v = *(const int4*)(base + (r << 10) + (tid << 2));
        mask |= (1u << v.x) | (1u << v.y) | (1u << v.z) | (1u << v.w);
    }

    // fold the 8 consecutive threads sharing a tile (within one wave)
    mask |= __shfl_xor(mask, 1);
    mask |= __shfl_xor(mask, 2);
    mask |= __shfl_xor(mask, 4);

    __shared__ unsigned tile_mask[32];
    if ((tid & 7) == 0) tile_mask[tid >> 3] = mask;
    __syncthreads();

    // ---- BCE terms: tile = tid>>3, classes c, c+8, c+16 ----
    const int tile = tid >> 3;
    const int n    = (bid << 5) + tile;           // global tile id
    const unsigned m = tile_mask[tile];
    float loss = 0.0f;
    #pragma unroll
    for (int j = 0; j < 3; ++j) {
        const int c = (tid & 7) + (j << 3);
        if (c < NUM_CLASSES) {
            const float x  = preds[n * NUM_CLASSES + c];
            const float tv = ((m >> c) & 1u) ? 1.0f : 0.0f;
            // stable BCE term: softplus(x) - t*x
            const float sp = fmaxf(x, 0.0f) + log1pf(__expf(-fabsf(x)));
            loss += sp - tv * x;
        }
    }

    // ---- block reduction ----
    loss += __shfl_xor(loss, 1);
    loss += __shfl_xor(loss, 2);
    loss += __shfl_xor(loss, 4);
    loss += __shfl_xor(loss, 8);
    loss += __shfl_xor(loss, 16);
    loss += __shfl_xor(loss, 32);

    __shared__ float wsum[4];
    if ((tid & 63) == 0) wsum[tid >> 6] = loss;
    __syncthreads();

    // ---- publish partial; last block reduces ----
    __shared__ bool am_last;
    if (tid == 0) {
        partial[bid] = wsum[0] + wsum[1] + wsum[2] + wsum[3];
        __threadfence();                           // release partial
        const int old = atomicAdd(counter, 1);     // device-scope
        am_last = (old == N_BLOCKS - 1);
    }
    __syncthreads();

    if (am_last) {
        __threadfence();                           // acquire all partials
        float s = 0.0f;
        for (int i = tid; i < N_BLOCKS; i += 256) s += partial[i];

        s += __shfl_xor(s, 1);
        s += __shfl_xor(s, 2);
        s += __shfl_xor(s, 4);
        s += __shfl_xor(s, 8);
        s += __shfl_xor(s, 16);
        s += __shfl_xor(s, 32);

        __shared__ float fsum[4];
        if ((tid & 63) == 0) fsum[tid >> 6] = s;
        __syncthreads();
        if (tid == 0)
            out[0] = (fsum[0] + fsum[1] + fsum[2] + fsum[3]) * inv_total;
    }
}

extern "C" void kernel_launch(void* const* d_in, const int* in_sizes, int n_in,
                              void* d_out, int out_size, void* d_ws, size_t ws_size,
                              hipStream_t stream) {
    const float* preds   = (const float*)d_in[0];
    const int*   targets = (const int*)d_in[1];
    float*       out     = (float*)d_out;
    int*         counter = (int*)d_ws;
    float*       partial = (float*)((char*)d_ws + 256);

    const int n_tiles = in_sizes[0] / NUM_CLASSES;   // 32768
    const float inv_total = 1.0f / (float)(n_tiles * NUM_CLASSES);

    // counter is poisoned 0xAA before every timed call — zero it (4 B only).
    hipMemsetAsync(counter, 0, sizeof(int), stream);

    seg_loss_fused<<<N_BLOCKS, 256, 0, stream>>>(preds, targets, out,
                                                 counter, partial, inv_total);
}

// Round 7
// 186.573 us; speedup vs baseline: 1.2944x; 1.2944x over previous
//
#include <hip/hip_runtime.h>

#define NUM_CLASSES 19

typedef int v4i __attribute__((ext_vector_type(4)));

// Round-5 structure (best: 197.7us) + NON-TEMPORAL target loads.
// Rationale: the harness's 512MB d_ws 0xAA fill dirties the whole 256MB L3
// right before our kernel; normal read-allocates evict ~128MB of dirty
// poison -> forced HBM writeback concurrent with our fetch (the invariant
// ~53us). global_load_dwordx4+nt still hits resident lines but doesn't
// allocate on miss -> no eviction tax, only the ~67MB compulsory fetch.
__global__ __launch_bounds__(256) void seg_loss_partial(
    const float* __restrict__ preds,
    const int*   __restrict__ targets,
    float*       __restrict__ partial)
{
    const int tid = threadIdx.x;
    // one block per 32x1024 slab (128 KB contiguous); base = bid*32768
    const int* base = targets + (blockIdx.x << 15);

    unsigned mask = 0u;
    #pragma unroll 4
    for (int r = 0; r < 32; ++r) {
        const v4i v = __builtin_nontemporal_load(
            (const v4i*)(base + (r << 10) + (tid << 2)));
        mask |= (1u << v.x) | (1u << v.y) | (1u << v.z) | (1u << v.w);
    }

    // fold the 8 consecutive threads sharing a tile (within one wave)
    mask |= __shfl_xor(mask, 1);
    mask |= __shfl_xor(mask, 2);
    mask |= __shfl_xor(mask, 4);

    __shared__ unsigned tile_mask[32];
    if ((tid & 7) == 0) tile_mask[tid >> 3] = mask;
    __syncthreads();

    // BCE terms: tile = tid>>3 (32 tiles x 8 threads), classes c, c+8, c+16
    const int tile = tid >> 3;
    const int n    = (blockIdx.x << 5) + tile;      // global tile id
    const unsigned m = tile_mask[tile];
    float loss = 0.0f;
    #pragma unroll
    for (int j = 0; j < 3; ++j) {
        const int c = (tid & 7) + (j << 3);
        if (c < NUM_CLASSES) {
            const float x  = preds[n * NUM_CLASSES + c];
            const float tv = ((m >> c) & 1u) ? 1.0f : 0.0f;
            // stable BCE term: softplus(x) - t*x
            const float sp = fmaxf(x, 0.0f) + log1pf(__expf(-fabsf(x)));
            loss += sp - tv * x;
        }
    }

    // block reduction
    loss += __shfl_xor(loss, 1);
    loss += __shfl_xor(loss, 2);
    loss += __shfl_xor(loss, 4);
    loss += __shfl_xor(loss, 8);
    loss += __shfl_xor(loss, 16);
    loss += __shfl_xor(loss, 32);

    __shared__ float wsum[4];
    if ((tid & 63) == 0) wsum[tid >> 6] = loss;
    __syncthreads();
    if (tid == 0)
        partial[blockIdx.x] = wsum[0] + wsum[1] + wsum[2] + wsum[3];
}

__global__ __launch_bounds__(256) void seg_loss_reduce(
    const float* __restrict__ partial,
    float*       __restrict__ out,
    float inv_total, int nblocks)
{
    float s = 0.0f;
    for (int i = threadIdx.x; i < nblocks; i += 256) s += partial[i];

    s += __shfl_xor(s, 1);
    s += __shfl_xor(s, 2);
    s += __shfl_xor(s, 4);
    s += __shfl_xor(s, 8);
    s += __shfl_xor(s, 16);
    s += __shfl_xor(s, 32);

    __shared__ float wsum[4];
    const int wave = threadIdx.x >> 6;
    const int lane = threadIdx.x & 63;
    if (lane == 0) wsum[wave] = s;
    __syncthreads();
    if (threadIdx.x == 0)
        out[0] = (wsum[0] + wsum[1] + wsum[2] + wsum[3]) * inv_total;
}

extern "C" void kernel_launch(void* const* d_in, const int* in_sizes, int n_in,
                              void* d_out, int out_size, void* d_ws, size_t ws_size,
                              hipStream_t stream) {
    const float* preds   = (const float*)d_in[0];
    const int*   targets = (const int*)d_in[1];
    float*       out     = (float*)d_out;
    float*       partial = (float*)d_ws;

    const int n_tiles  = in_sizes[0] / NUM_CLASSES;   // 32768
    const int n_blocks = n_tiles / 32;                // 1024 slabs
    const float inv_total = 1.0f / (float)(n_tiles * NUM_CLASSES);

    seg_loss_partial<<<n_blocks, 256, 0, stream>>>(preds, targets, partial);
    seg_loss_reduce<<<1, 256, 0, stream>>>(partial, out, inv_total, n_blocks);
}